// Round 11
// baseline (345.132 us; speedup 1.0000x reference)
//
#include <hip/hip_runtime.h>
#include <math.h>

#define B_  4
#define T_  1024
#define C_  1024
#define H_  16
#define HS_ 64
#define K2E 0.1803368801f   // 0.125 * log2(e)
#define LOG2E 1.44269504f

typedef _Float16 f16;
typedef _Float16 f16x8 __attribute__((ext_vector_type(8)));
typedef _Float16 f16x4 __attribute__((ext_vector_type(4)));
typedef float f32x4 __attribute__((ext_vector_type(4)));

#define MFMA16(a,b,c) __builtin_amdgcn_mfma_f32_16x16x32_f16(a,b,c,0,0,0)
#define EXP2(x) __builtin_amdgcn_exp2f(x)
#define RCP(x)  __builtin_amdgcn_rcpf(x)

// Pbuf: causal-packed scores per (bh, g-tile):
//   base = bh*PSTRIDE_BH + 4096*g*(g+1)/2, row stride S = (g+1)*64, 64 rows.
#define PSTRIDE_BH 557056   // 4096 * 136

__device__ __forceinline__ float qsum_(float v){
    v += __shfl_xor(v,1,64); v += __shfl_xor(v,2,64);
    v += __shfl_xor(v,4,64); v += __shfl_xor(v,8,64);
    return v;
}
__device__ __forceinline__ float sigmoidf_(float x){ return 1.0f/(1.0f + __expf(-x)); }
__device__ __forceinline__ float softplusf_(float x){ return fmaxf(x, 0.0f) + log1pf(__expf(-fabsf(x))); }

// async global->LDS DMA, 16B per lane; lds base must be wave-uniform.
__device__ __forceinline__ void gload_lds16(const f16* g, f16* l){
    __builtin_amdgcn_global_load_lds(
        (__attribute__((address_space(1))) void*)(void*)g,
        (__attribute__((address_space(3))) void*)(void*)l, 16, 0, 0);
}

// ---------------------------------------------------------------------------
// prep: 0..2047 x->f16; 2048..5119 W_attn^T; 5120..6143 W_proj^T; rest zero.
// ---------------------------------------------------------------------------
__global__ __launch_bounds__(256) void prep_k(
    const float* __restrict__ x, const float* __restrict__ Wa,
    const float* __restrict__ Wp,
    f16* __restrict__ x_h, f16* __restrict__ WaT, f16* __restrict__ WpT,
    float* __restrict__ zbase)
{
    __shared__ float tl[32][33];
    const int bid = blockIdx.x, tid = threadIdx.x;
    if (bid < 2048){
        int i = bid*256 + tid;
        const float4* p = (const float4*)x + (size_t)i*2;
        float4 a = p[0], b = p[1];
        f16x8 o;
        o[0]=(f16)a.x; o[1]=(f16)a.y; o[2]=(f16)a.z; o[3]=(f16)a.w;
        o[4]=(f16)b.x; o[5]=(f16)b.y; o[6]=(f16)b.z; o[7]=(f16)b.w;
        *((f16x8*)x_h + i) = o;
    } else if (bid < 5120){
        int t = bid - 2048;
        int n0 = (t % 96)*32, k0 = (t / 96)*32;
        const int c = tid & 31, r4 = tid >> 5;
        #pragma unroll
        for (int i=0;i<4;i++){ int r = r4*4+i; tl[r][c] = Wa[(size_t)(k0+r)*3072 + n0 + c]; }
        __syncthreads();
        #pragma unroll
        for (int i=0;i<4;i++){ int r = r4*4+i; WaT[(size_t)(n0+r)*1024 + k0 + c] = (f16)tl[c][r]; }
    } else if (bid < 6144){
        int t = bid - 5120;
        int n0 = (t & 31)*32, k0 = (t >> 5)*32;
        const int c = tid & 31, r4 = tid >> 5;
        #pragma unroll
        for (int i=0;i<4;i++){ int r = r4*4+i; tl[r][c] = Wp[(size_t)(k0+r)*1024 + n0 + c]; }
        __syncthreads();
        #pragma unroll
        for (int i=0;i<4;i++){ int r = r4*4+i; WpT[(size_t)(n0+r)*1024 + k0 + c] = (f16)tl[c][r]; }
    } else {
        int idx = (bid - 6144)*256 + tid;   // 17408 float4 = colp + racc
        float4 z; z.x=0.f; z.y=0.f; z.z=0.f; z.w=0.f;
        ((float4*)zbase)[idx] = z;
    }
}

// ---------------------------------------------------------------------------
// GEMM qkv: 128x128x32, global_load_lds direct staging, XCD-chunked swizzle.
// Epilogue: Q/K blocks stage Ct row-major; V blocks stage Ct TRANSPOSED
// (stride 136 f16) so the d-major gather is vectorized.
// ---------------------------------------------------------------------------
#define CT_STRIDE  132
#define CTV_STRIDE 136
__global__ __launch_bounds__(256) void gemm_qkv_k(
    const f16* __restrict__ A, const f16* __restrict__ Bt,
    const float* __restrict__ bias,
    f16* __restrict__ Qh, f16* __restrict__ Kh, f16* __restrict__ Vt)
{
    __shared__ __align__(16) f16 smem[17408];  // buf0 0..8191, buf1 8192..16383; Ct aliases
    const int tid = threadIdx.x;
    const int lane = tid & 63, wave = tid >> 6;
    const int lx = lane & 15, quad = lane >> 4;
    const int wm = wave & 1, wn = wave >> 1;
    const int lin = blockIdx.y*24 + blockIdx.x;       // 0..767
    const int nb  = (lin & 7)*96 + (lin >> 3);        // bijective XCD chunking
    const int m0 = (nb/24)*128, n0 = (nb%24)*128;
    const f16* Ap = A  + (size_t)m0*1024;
    const f16* Bp = Bt + (size_t)n0*1024;
    f32x4 acc[4][4];
    #pragma unroll
    for (int i=0;i<4;i++){
        #pragma unroll
        for (int j=0;j<4;j++){ acc[i][j][0]=0.f;acc[i][j][1]=0.f;acc[i][j][2]=0.f;acc[i][j][3]=0.f; }
    }
#define GQ_STAGE(BUF, KT) { \
    const int k0s = (KT)*32; \
    for (int i=0;i<2;i++){ int c=i*4+wave; \
        gload_lds16(Ap + (size_t)(c*16+lx)*1024 + k0s + quad*8, &smem[(BUF) + c*512]); \
        gload_lds16(Bp + (size_t)(c*16+lx)*1024 + k0s + quad*8, &smem[(BUF) + 4096 + c*512]); } }
#define GQ_COMP(BUF) { \
    f16x8 af[4], bf[4]; \
    for (int mt=0;mt<4;mt++) af[mt] = *(const f16x8*)&smem[(BUF) + (wm*4+mt)*512 + quad*128 + lx*8]; \
    for (int nt=0;nt<4;nt++) bf[nt] = *(const f16x8*)&smem[(BUF) + 4096 + (wn*4+nt)*512 + quad*128 + lx*8]; \
    for (int mt=0;mt<4;mt++) \
        for (int nt=0;nt<4;nt++) \
            acc[mt][nt] = MFMA16(af[mt], bf[nt], acc[mt][nt]); }

    GQ_STAGE(0, 0);
    __syncthreads();
    #pragma unroll 1
    for (int it=0; it<32; it+=2){
        if (it+1 < 32) GQ_STAGE(8192, it+1);
        GQ_COMP(0);
        __syncthreads();
        if (it+2 < 32) GQ_STAGE(0, it+2);
        GQ_COMP(8192);
        __syncthreads();
    }
    // epilogue: C-tile -> LDS -> dense f16x8 stores
    f16* Ct = smem;
    const bool isV = (n0 >= 2048);
    if (!isV){
        #pragma unroll
        for (int mt=0;mt<4;mt++){
            #pragma unroll
            for (int nt=0;nt<4;nt++){
                int n_loc = wn*64 + nt*16 + lx;
                float bv = bias[n0 + n_loc];
                #pragma unroll
                for (int r=0;r<4;r++){
                    int m_loc = wm*64 + mt*16 + quad*4 + r;
                    Ct[m_loc*CT_STRIDE + n_loc] = (f16)(acc[mt][nt][r] + bv);
                }
            }
        }
    } else {
        // transposed staging: Ct_t[n][m], r-quad contiguous -> f16x4 writes
        #pragma unroll
        for (int mt=0;mt<4;mt++){
            #pragma unroll
            for (int nt=0;nt<4;nt++){
                int n_loc = wn*64 + nt*16 + lx;
                float bv = bias[n0 + n_loc];
                int m_base = wm*64 + mt*16 + quad*4;
                f16x4 t4;
                #pragma unroll
                for (int r=0;r<4;r++) t4[r] = (f16)(acc[mt][nt][r] + bv);
                *(f16x4*)&Ct[n_loc*CTV_STRIDE + m_base] = t4;
            }
        }
    }
    __syncthreads();
    const int bb = m0 >> 10;
    if (!isV){
        for (int it=0; it<8; it++){
            int row = it*32 + wave*8 + (lane>>3);
            int ch  = lane & 7;
            int m_loc = row >> 1, half = row & 1;
            f16x8 v = *(const f16x8*)&Ct[m_loc*CT_STRIDE + half*64 + ch*8];
            int n = n0 + half*64;
            int which = n >> 10, cc = n & 1023, h = cc >> 6;
            int t = (m0 + m_loc) & 1023;
            f16* dst = (which==0) ? Qh : Kh;
            *(f16x8*)(dst + ((size_t)(bb*16+h)*1024 + t)*64 + ch*8) = v;
        }
    } else {
        for (int it=0; it<8; it++){
            int drow = it*16 + wave*4 + (lane>>4);
            int ch   = lane & 15;
            f16x8 v = *(const f16x8*)&Ct[drow*CTV_STRIDE + ch*8];
            int cc = (n0 + drow) & 1023;
            int h = cc >> 6, d = cc & 63;
            int t = (m0 + ch*8) & 1023;
            *(f16x8*)(Vt + ((size_t)(bb*16+h)*64 + d)*1024 + t) = v;
        }
    }
}

// ---------------------------------------------------------------------------
// GEMM proj: 128x64x32, global_load_lds staging + XCD swizzle; block 512 =
// finish_refr.
// ---------------------------------------------------------------------------
__global__ __launch_bounds__(256) void gemm_proj_k(
    const f16* __restrict__ A, const f16* __restrict__ Bt,
    const float* __restrict__ bias, float* __restrict__ out,
    const float* __restrict__ racc)
{
    if (blockIdx.x == 512){
        float* oref = out + (size_t)B_*T_*C_;
        #pragma unroll
        for (int j=0;j<16;j++){
            int idx = j*256 + threadIdx.x;
            oref[idx] = racc[idx] * (1.0f/(H_*T_));
        }
        return;
    }
    __shared__ __align__(16) f16 smem[12288];  // buf0 0..6143, buf1 6144..12287
    const int tid = threadIdx.x;
    const int lane = tid & 63, wave = tid >> 6;
    const int lx = lane & 15, quad = lane >> 4;
    const int wm = wave & 1, wn = wave >> 1;
    const int lin = blockIdx.x;                      // 0..511
    const int nb  = (lin & 7)*64 + (lin >> 3);       // bijective XCD chunking
    const int m0 = (nb >> 4)*128, n0 = (nb & 15)*64;
    const f16* Ap = A  + (size_t)m0*1024;
    const f16* Bp = Bt + (size_t)n0*1024;
    f32x4 acc[4][2];
    #pragma unroll
    for (int i=0;i<4;i++){
        #pragma unroll
        for (int j=0;j<2;j++){ acc[i][j][0]=0.f;acc[i][j][1]=0.f;acc[i][j][2]=0.f;acc[i][j][3]=0.f; }
    }
#define GP_STAGE(BUF, KT) { \
    const int k0s = (KT)*32; \
    for (int i=0;i<2;i++){ int c=i*4+wave; \
        gload_lds16(Ap + (size_t)(c*16+lx)*1024 + k0s + quad*8, &smem[(BUF) + c*512]); } \
    gload_lds16(Bp + (size_t)(wave*16+lx)*1024 + k0s + quad*8, &smem[(BUF) + 4096 + wave*512]); }
#define GP_COMP(BUF) { \
    f16x8 af[4], bf[2]; \
    for (int mt=0;mt<4;mt++) af[mt] = *(const f16x8*)&smem[(BUF) + (wm*4+mt)*512 + quad*128 + lx*8]; \
    for (int nt=0;nt<2;nt++) bf[nt] = *(const f16x8*)&smem[(BUF) + 4096 + (wn*2+nt)*512 + quad*128 + lx*8]; \
    for (int mt=0;mt<4;mt++) \
        for (int nt=0;nt<2;nt++) \
            acc[mt][nt] = MFMA16(af[mt], bf[nt], acc[mt][nt]); }

    GP_STAGE(0, 0);
    __syncthreads();
    #pragma unroll 1
    for (int it=0; it<32; it+=2){
        if (it+1 < 32) GP_STAGE(6144, it+1);
        GP_COMP(0);
        __syncthreads();
        if (it+2 < 32) GP_STAGE(0, it+2);
        GP_COMP(6144);
        __syncthreads();
    }
    #pragma unroll
    for (int mt=0;mt<4;mt++){
        #pragma unroll
        for (int nt=0;nt<2;nt++){
            int n = n0 + wn*32 + nt*16 + lx;
            float bv = bias[n];
            #pragma unroll
            for (int r=0;r<4;r++){
                int m = m0 + wm*64 + mt*16 + quad*4 + r;
                out[(size_t)m*1024 + n] = acc[mt][nt][r] + bv;
            }
        }
    }
}

// ---------------------------------------------------------------------------
// attn_stats (R4 known-good): LDS-staged K dbuf, single compute sweep ->
// Pbuf + row sums; reread -> colp column sums.
// ---------------------------------------------------------------------------
__global__ __launch_bounds__(256) void attn_stats_k(
    const f16* __restrict__ Qh, const f16* __restrict__ Kh,
    float* __restrict__ rowl, float* __restrict__ colp,
    f16* __restrict__ Pbuf)
{
    __shared__ __align__(16) f16 Kl[8192];   // bufA 0..4095, bufB 4096..8191
    __shared__ __align__(16) f16 Pl[4][16*72];
    __shared__ float invl_sh[64];
    const int tid = threadIdx.x;
    const int lane = tid & 63, wave = tid >> 6;
    const int lx = lane & 15, quad = lane >> 4;
    const int g  = 15 - (blockIdx.x >> 6);
    const int bh = blockIdx.x & 63;
    const int qpos = wave*16 + quad*4;
    const size_t kbase = (size_t)bh*65536;
    const int S = (g+1)*64;
    f16* __restrict__ Pblk = Pbuf + (size_t)bh*PSTRIDE_BH + (size_t)4096*((g*(g+1))>>1);

    const size_t qoff = ((size_t)bh*1024 + g*64 + wave*16 + lx)*64;
    f16x8 aq0 = *(const f16x8*)(Qh + qoff + quad*8);
    f16x8 aq1 = *(const f16x8*)(Qh + qoff + 32 + quad*8);

#define KLOAD(dst, KT) { \
    for (int i=0;i<2;i++){ int u=i*4+wave, cc=u&3, kh=u>>2; \
        dst[i] = *(const f16x8*)(Kh + kbase + (size_t)((KT)*64 + cc*16+lx)*64 + kh*32 + quad*8); } }
#define KSTORE(src, BUF) { \
    for (int i=0;i<2;i++){ int u=i*4+wave, cc=u&3, kh=u>>2; \
        *(f16x8*)&Kl[(BUF) + cc*1024 + kh*512 + quad*128 + lx*8] = src[i]; } }
#define STATS1_TILE(KT, BUF) { \
    const bool diag = ((KT) == g); \
    for (int nt=0;nt<4;nt++){ \
        f32x4 sc = {0.f,0.f,0.f,0.f}; \
        f16x8 b0 = *(const f16x8*)&Kl[(BUF) + nt*1024 + quad*128 + lx*8]; \
        f16x8 b1 = *(const f16x8*)&Kl[(BUF) + nt*1024 + 512 + quad*128 + lx*8]; \
        sc = MFMA16(aq0, b0, sc); \
        sc = MFMA16(aq1, b1, sc); \
        for (int r=0;r<4;r++){ \
            float sv = sc[r]; \
            if (diag && (nt*16+lx) > (qpos + r)) sv = -1e4f; \
            float p = EXP2(sv*K2E); \
            ls[r] += p; \
            Pl[wave][(quad*4+r)*72 + nt*16 + lx] = (f16)p; \
        } } \
    for (int it2=0; it2<2; it2++){ \
        int qq = it2*8 + (lane>>3), chh = lane & 7; \
        f16x8 v = *(const f16x8*)&Pl[wave][qq*72 + chh*8]; \
        *(f16x8*)(Pblk + (size_t)(wave*16+qq)*S + (KT)*64 + chh*8) = v; } }

    f16x8 rkE[2], rkO[2];
    float ls[4] = {0.f,0.f,0.f,0.f};
    // ---- single compute sweep ----
    KLOAD(rkE, 0);
    KSTORE(rkE, 0);
    if (g >= 1) KLOAD(rkO, 1);
    __syncthreads();
    #pragma unroll 1
    for (int kt=0; kt<=g; kt+=2){
        if (kt+2 <= g) KLOAD(rkE, kt+2);
        if (kt+1 <= g) KSTORE(rkO, 4096);
        STATS1_TILE(kt, 0);
        __syncthreads();
        if (kt+1 <= g){
            if (kt+3 <= g) KLOAD(rkO, kt+3);
            if (kt+2 <= g) KSTORE(rkE, 0);
            STATS1_TILE(kt+1, 4096);
            __syncthreads();
        }
    }
    #pragma unroll
    for (int r=0;r<4;r++){
        float l = qsum_(ls[r]);
        if (lx == 0){
            rowl[(size_t)bh*1024 + g*64 + qpos + r] = l;
            invl_sh[qpos + r] = RCP(l);
        }
    }
    __syncthreads();   // invl_sh + Pblk global writes visible block-wide
    // ---- reread sweep: column sums of probs ----
    if (tid < (g+1)*16){
        const int k0 = tid*4;
        float a0=0.f, a1=0.f, a2=0.f, a3=0.f;
        const f16* pr = Pblk + k0;
        #pragma unroll 4
        for (int q=0;q<64;q++){
            f16x4 v = *(const f16x4*)(pr + (size_t)q*S);
            float w = invl_sh[q];
            a0 += (float)v[0]*w; a1 += (float)v[1]*w;
            a2 += (float)v[2]*w; a3 += (float)v[3]*w;
        }
        float* cp = colp + (size_t)bh*1024 + k0;
        atomicAdd(cp+0,a0); atomicAdd(cp+1,a1);
        atomicAdd(cp+2,a2); atomicAdd(cp+3,a3);
    }
}

// ---------------------------------------------------------------------------
// attn_apply: q-SPLIT grid — 2048 blocks x 128 threads (2 waves), each block
// handles 32 q-rows (half a g-tile). Doubles schedulable block supply (the
// measured occupancy cap was grid-size, 4 blocks/CU). R8 inner structure:
// LDS-staged V dbuf + in-register LIF in the MFMA A-fragment layout; Pl
// aliased into Vl for the Yh epilogue; reread recomputes LIF (f32).
// ---------------------------------------------------------------------------
__global__ __launch_bounds__(128) void attn_apply_k(
    const f16* __restrict__ Vt,
    const float* __restrict__ rowl,
    const float* __restrict__ colp, const float* __restrict__ refr,
    const float* __restrict__ threshold, const float* __restrict__ leak,
    const float* __restrict__ steepness, const float* __restrict__ ref_strength,
    const float* __restrict__ cross_w,
    f16* __restrict__ Yh, float* __restrict__ racc,
    f16* __restrict__ Pbuf)
{
    __shared__ __align__(16) f16 Vl[8192];   // main loop V dbuf; epilogue Pl alias
    __shared__ float eb[1024];
    __shared__ float invl_sh[32];
    __shared__ float invD_sh[32];
    const int tid = threadIdx.x;             // 0..127
    const int lane = tid & 63, wave = tid >> 6;   // wave 0..1
    const int lx = lane & 15, quad = lane >> 4;
    const int gq = blockIdx.x >> 6;          // 0..31 (long-first)
    const int g  = 15 - (gq >> 1);
    const int half = gq & 1;
    const int bh = blockIdx.x & 63;
    const int b  = bh >> 4, h = bh & 15;
    const int q0 = half*32;                  // this block's q-row base in the tile
    const size_t kbase = (size_t)bh*65536;
    const int S = (g+1)*64;
    f16* __restrict__ Pblk = Pbuf + (size_t)bh*PSTRIDE_BH + (size_t)4096*((g*(g+1))>>1);

    const float thr = fabsf(threshold[h])*0.1f;
    const float lk  = sigmoidf_(leak[h]);
    const float st2 = softplusf_(steepness[h]) * LOG2E;
    const float sprT= softplusf_(ref_strength[h]) * (1.0f/T_);
    const float cw  = sigmoidf_(cross_w[h]);
    const float Alk = 1.f - lk;

    {   // eb init: 128 threads x 8 entries
        #pragma unroll
        for (int s=0; s<2; s++){
            int base = tid*8 + s*4;
            float4 cp = *(const float4*)(colp + (size_t)bh*1024 + base);
            float4 rf = *(const float4*)(refr + (size_t)b*1024 + base);
            eb[base+0] = st2*(thr + sprT*cp.x + cw*rf.x);
            eb[base+1] = st2*(thr + sprT*cp.y + cw*rf.y);
            eb[base+2] = st2*(thr + sprT*cp.z + cw*rf.z);
            eb[base+3] = st2*(thr + sprT*cp.w + cw*rf.w);
        }
    }
    if (tid < 32) invl_sh[tid] = RCP(rowl[(size_t)bh*1024 + g*64 + q0 + tid]);
    __syncthreads();   // eb + invl_sh visible

    const float wli = invl_sh[wave*16 + lx];   // this lane's row 1/l

    f32x4 y[4];
    #pragma unroll
    for (int i=0;i<4;i++){ y[i][0]=0.f;y[i][1]=0.f;y[i][2]=0.f;y[i][3]=0.f; }
    float Dp = 0.f;

// 2 waves cover the 8 V chunks: u = i*2 + wave, i=0..3
#define VLOAD(dst, KT) { \
    for (int i=0;i<4;i++){ int u=i*2+wave, cc=u&3, kh=u>>2; \
        dst[i] = *(const f16x8*)(Vt + kbase + (size_t)(cc*16+lx)*1024 + (KT)*64 + kh*32 + quad*8); } }
#define VSTORE(src, BUF) { \
    for (int i=0;i<4;i++){ int u=i*2+wave, cc=u&3, kh=u>>2; \
        *(f16x8*)&Vl[(BUF) + cc*1024 + kh*512 + quad*128 + lx*8] = src[i]; } }
// p A-fragment loads: row = q0 + wave*16 + lx
#define PLOADX(dst, KT) { \
    const f16* pp = Pblk + (size_t)(q0 + wave*16 + lx)*S + (KT)*64 + quad*8; \
    dst[0] = *(const f16x8*)(pp); \
    dst[1] = *(const f16x8*)(pp + 32); }
#define APPLY_T(KT, BUF, pv) { \
    const float* ebp = &eb[(KT)*64 + quad*8]; \
    float4 eA0 = *(const float4*)(ebp); \
    float4 eA1 = *(const float4*)(ebp+4); \
    float4 eB0 = *(const float4*)(ebp+32); \
    float4 eB1 = *(const float4*)(ebp+36); \
    float ea[8] = {eA0.x,eA0.y,eA0.z,eA0.w,eA1.x,eA1.y,eA1.z,eA1.w}; \
    float ebb[8] = {eB0.x,eB0.y,eB0.z,eB0.w,eB1.x,eB1.y,eB1.z,eB1.w}; \
    f16x8 af0, af1; \
    for (int jj=0;jj<8;jj++){ \
        float p = (float)pv[0][jj] * wli; \
        float fire = RCP(1.f + EXP2(ea[jj] - st2*p)); \
        float pw = p*(lk + Alk*fire); \
        Dp += pw; af0[jj] = (f16)pw; } \
    for (int jj=0;jj<8;jj++){ \
        float p = (float)pv[1][jj] * wli; \
        float fire = RCP(1.f + EXP2(ebb[jj] - st2*p)); \
        float pw = p*(lk + Alk*fire); \
        Dp += pw; af1[jj] = (f16)pw; } \
    for (int dt=0;dt<4;dt++){ \
        f16x8 bv0 = *(const f16x8*)&Vl[(BUF) + dt*1024 + quad*128 + lx*8]; \
        f16x8 bv1 = *(const f16x8*)&Vl[(BUF) + dt*1024 + 512 + quad*128 + lx*8]; \
        y[dt] = MFMA16(af0, bv0, y[dt]); \
        y[dt] = MFMA16(af1, bv1, y[dt]); } }

    f16x8 rvE[4], rvO[4], pvE[2], pvO[2];
    VLOAD(rvE, 0); PLOADX(pvE, 0);
    VSTORE(rvE, 0);
    if (g >= 1){ VLOAD(rvO, 1); PLOADX(pvO, 1); }
    __syncthreads();
    #pragma unroll 1
    for (int kt=0; kt<=g; kt+=2){
        if (kt+2 <= g) VLOAD(rvE, kt+2);
        if (kt+1 <= g) VSTORE(rvO, 4096);
        APPLY_T(kt, 0, pvE);
        if (kt+2 <= g) PLOADX(pvE, kt+2);
        __syncthreads();
        if (kt+1 <= g){
            if (kt+3 <= g) VLOAD(rvO, kt+3);
            if (kt+2 <= g) VSTORE(rvE, 0);
            APPLY_T(kt+1, 4096, pvO);
            if (kt+3 <= g) PLOADX(pvO, kt+3);
            __syncthreads();
        }
    }
    // row-sum D reduce across the 4 quad lanes of each row (row = wave*16+lx)
    Dp += __shfl_xor(Dp,16,64); Dp += __shfl_xor(Dp,32,64);
    if (quad == 0) invD_sh[wave*16 + lx] = RCP(Dp + 1e-8f);

    // y normalize -> Yh via Pl alias of Vl (all Vl reads precede the last
    // main-loop barrier; per-wave region; same-wave invD_sh write->read)
    f16* Plw = Vl + wave*1152;   // 16 x 72
    float invD[4];
    #pragma unroll
    for (int r=0;r<4;r++) invD[r] = invD_sh[wave*16 + quad*4 + r];
    #pragma unroll
    for (int dt=0;dt<4;dt++){
        #pragma unroll
        for (int r=0;r<4;r++)
            Plw[(quad*4+r)*72 + dt*16 + lx] = (f16)(y[dt][r]*invD[r]);
    }
    #pragma unroll
    for (int it=0; it<2; it++){
        int q = it*8 + (lane>>3), ch = lane & 7;
        f16x8 v = *(const f16x8*)&Plw[q*72 + ch*8];
        *(f16x8*)(Yh + (size_t)(b*1024 + g*64 + q0 + wave*16 + q)*1024 + h*64 + ch*8) = v;
    }

    __syncthreads();   // both waves' invD_sh visible

    // ---- reread sweep: recompute pw from p (f32) over own 32 rows ----
    if (tid < (g+1)*8){
        const int k0 = tid*8;
        float4 e0 = *(const float4*)&eb[k0];
        float4 e1 = *(const float4*)&eb[k0+4];
        float ebv[8] = {e0.x,e0.y,e0.z,e0.w,e1.x,e1.y,e1.z,e1.w};
        float a[8] = {0.f,0.f,0.f,0.f,0.f,0.f,0.f,0.f};
        const f16* pr = Pblk + (size_t)q0*S + k0;
        #pragma unroll 4
        for (int q=0;q<32;q++){
            f16x8 v = *(const f16x8*)(pr + (size_t)q*S);
            float wl = invl_sh[q], wd = invD_sh[q];
            #pragma unroll
            for (int j=0;j<8;j++){
                float p = (float)v[j]*wl;
                float f = RCP(1.f + EXP2(ebv[j] - st2*p));
                a[j] += p*(lk + Alk*f)*wd;
            }
        }
        float* rp = racc + (size_t)b*1024 + k0;
        #pragma unroll
        for (int j=0;j<8;j++) atomicAdd(rp+j, a[j]);
    }
}

// ---------------------------------------------------------------------------
extern "C" void kernel_launch(void* const* d_in, const int* in_sizes, int n_in,
                              void* d_out, int out_size, void* d_ws, size_t ws_size,
                              hipStream_t stream) {
    (void)in_sizes; (void)n_in; (void)out_size; (void)ws_size;
    const float* x           = (const float*)d_in[0];
    const float* refr        = (const float*)d_in[1];
    const float* W_attn      = (const float*)d_in[2];
    const float* b_attn      = (const float*)d_in[3];
    const float* W_proj      = (const float*)d_in[4];
    const float* b_proj      = (const float*)d_in[5];
    const float* threshold   = (const float*)d_in[6];
    const float* leak        = (const float*)d_in[7];
    const float* steepness   = (const float*)d_in[8];
    const float* ref_strength= (const float*)d_in[9];
    const float* cross_w     = (const float*)d_in[10];
    float* out = (float*)d_out;

    char* ws = (char*)d_ws;
    f16* x_h = (f16*)ws;                       ws += (size_t)4096*1024*2;
    f16* WaT = (f16*)ws;                       ws += (size_t)3072*1024*2;
    f16* WpT = (f16*)ws;                       ws += (size_t)1024*1024*2;
    f16* Qh  = (f16*)ws;                       ws += (size_t)64*1024*64*2;
    f16* Kh  = (f16*)ws;                       ws += (size_t)64*1024*64*2;
    f16* Vt  = (f16*)ws;                       ws += (size_t)64*64*1024*2;
    f16* Yh  = (f16*)ws;                       ws += (size_t)4096*1024*2;
    float* rowl = (float*)ws;                  ws += (size_t)65536*4;
    float* colp = (float*)ws;                  ws += (size_t)65536*4;
    float* racc = (float*)ws;                  ws += (size_t)4096*4;   // adjacent to colp!
    f16* Pbuf = (f16*)ws;                      ws += (size_t)64*PSTRIDE_BH*2;

    prep_k<<<dim3(6212), dim3(256), 0, stream>>>(x, W_attn, W_proj, x_h, WaT, WpT, colp);
    gemm_qkv_k<<<dim3(24,32), dim3(256), 0, stream>>>(x_h, WaT, b_attn, Qh, Kh, Vt);
    attn_stats_k<<<dim3(1024), dim3(256), 0, stream>>>(Qh, Kh, rowl, colp, Pbuf);
    attn_apply_k<<<dim3(2048), dim3(128), 0, stream>>>(
        Vt, rowl, colp, refr,
        threshold, leak, steepness, ref_strength, cross_w, Yh, racc, Pbuf);
    gemm_proj_k<<<dim3(513), dim3(256), 0, stream>>>(Yh, WpT, b_proj, out, racc);
}

// Round 12
// 258.154 us; speedup vs baseline: 1.3369x; 1.3369x over previous
//
#include <hip/hip_runtime.h>
#include <math.h>

#define B_  4
#define T_  1024
#define C_  1024
#define H_  16
#define HS_ 64
#define K2E 0.1803368801f   // 0.125 * log2(e)
#define LOG2E 1.44269504f

typedef _Float16 f16;
typedef _Float16 f16x8 __attribute__((ext_vector_type(8)));
typedef _Float16 f16x4 __attribute__((ext_vector_type(4)));
typedef float f32x4 __attribute__((ext_vector_type(4)));

#define MFMA16(a,b,c) __builtin_amdgcn_mfma_f32_16x16x32_f16(a,b,c,0,0,0)
#define EXP2(x) __builtin_amdgcn_exp2f(x)
#define RCP(x)  __builtin_amdgcn_rcpf(x)

// Pbuf: causal-packed scores per (bh, g-tile):
//   base = bh*PSTRIDE_BH + 4096*g*(g+1)/2, row stride S = (g+1)*64, 64 rows.
#define PSTRIDE_BH 557056   // 4096 * 136

__device__ __forceinline__ float qsum_(float v){
    v += __shfl_xor(v,1,64); v += __shfl_xor(v,2,64);
    v += __shfl_xor(v,4,64); v += __shfl_xor(v,8,64);
    return v;
}
__device__ __forceinline__ float sigmoidf_(float x){ return 1.0f/(1.0f + __expf(-x)); }
__device__ __forceinline__ float softplusf_(float x){ return fmaxf(x, 0.0f) + log1pf(__expf(-fabsf(x))); }

// async global->LDS DMA, 16B per lane; lds base must be wave-uniform.
__device__ __forceinline__ void gload_lds16(const f16* g, f16* l){
    __builtin_amdgcn_global_load_lds(
        (__attribute__((address_space(1))) void*)(void*)g,
        (__attribute__((address_space(3))) void*)(void*)l, 16, 0, 0);
}

// ---------------------------------------------------------------------------
// prep: 0..2047 x->f16; 2048..5119 W_attn^T; 5120..6143 W_proj^T; rest zero.
// ---------------------------------------------------------------------------
__global__ __launch_bounds__(256) void prep_k(
    const float* __restrict__ x, const float* __restrict__ Wa,
    const float* __restrict__ Wp,
    f16* __restrict__ x_h, f16* __restrict__ WaT, f16* __restrict__ WpT,
    float* __restrict__ zbase)
{
    __shared__ float tl[32][33];
    const int bid = blockIdx.x, tid = threadIdx.x;
    if (bid < 2048){
        int i = bid*256 + tid;
        const float4* p = (const float4*)x + (size_t)i*2;
        float4 a = p[0], b = p[1];
        f16x8 o;
        o[0]=(f16)a.x; o[1]=(f16)a.y; o[2]=(f16)a.z; o[3]=(f16)a.w;
        o[4]=(f16)b.x; o[5]=(f16)b.y; o[6]=(f16)b.z; o[7]=(f16)b.w;
        *((f16x8*)x_h + i) = o;
    } else if (bid < 5120){
        int t = bid - 2048;
        int n0 = (t % 96)*32, k0 = (t / 96)*32;
        const int c = tid & 31, r4 = tid >> 5;
        #pragma unroll
        for (int i=0;i<4;i++){ int r = r4*4+i; tl[r][c] = Wa[(size_t)(k0+r)*3072 + n0 + c]; }
        __syncthreads();
        #pragma unroll
        for (int i=0;i<4;i++){ int r = r4*4+i; WaT[(size_t)(n0+r)*1024 + k0 + c] = (f16)tl[c][r]; }
    } else if (bid < 6144){
        int t = bid - 5120;
        int n0 = (t & 31)*32, k0 = (t >> 5)*32;
        const int c = tid & 31, r4 = tid >> 5;
        #pragma unroll
        for (int i=0;i<4;i++){ int r = r4*4+i; tl[r][c] = Wp[(size_t)(k0+r)*1024 + n0 + c]; }
        __syncthreads();
        #pragma unroll
        for (int i=0;i<4;i++){ int r = r4*4+i; WpT[(size_t)(n0+r)*1024 + k0 + c] = (f16)tl[c][r]; }
    } else {
        int idx = (bid - 6144)*256 + tid;   // 17408 float4 = colp + racc
        float4 z; z.x=0.f; z.y=0.f; z.z=0.f; z.w=0.f;
        ((float4*)zbase)[idx] = z;
    }
}

// ---------------------------------------------------------------------------
// GEMM qkv: 128x128x32, global_load_lds direct staging, XCD-chunked swizzle.
// Epilogue: Q/K blocks stage Ct row-major; V blocks stage Ct TRANSPOSED
// (stride 136 f16) so the d-major gather is vectorized.
// ---------------------------------------------------------------------------
#define CT_STRIDE  132
#define CTV_STRIDE 136
__global__ __launch_bounds__(256) void gemm_qkv_k(
    const f16* __restrict__ A, const f16* __restrict__ Bt,
    const float* __restrict__ bias,
    f16* __restrict__ Qh, f16* __restrict__ Kh, f16* __restrict__ Vt)
{
    __shared__ __align__(16) f16 smem[17408];  // buf0 0..8191, buf1 8192..16383; Ct aliases
    const int tid = threadIdx.x;
    const int lane = tid & 63, wave = tid >> 6;
    const int lx = lane & 15, quad = lane >> 4;
    const int wm = wave & 1, wn = wave >> 1;
    const int lin = blockIdx.y*24 + blockIdx.x;       // 0..767
    const int nb  = (lin & 7)*96 + (lin >> 3);        // bijective XCD chunking
    const int m0 = (nb/24)*128, n0 = (nb%24)*128;
    const f16* Ap = A  + (size_t)m0*1024;
    const f16* Bp = Bt + (size_t)n0*1024;
    f32x4 acc[4][4];
    #pragma unroll
    for (int i=0;i<4;i++){
        #pragma unroll
        for (int j=0;j<4;j++){ acc[i][j][0]=0.f;acc[i][j][1]=0.f;acc[i][j][2]=0.f;acc[i][j][3]=0.f; }
    }
#define GQ_STAGE(BUF, KT) { \
    const int k0s = (KT)*32; \
    for (int i=0;i<2;i++){ int c=i*4+wave; \
        gload_lds16(Ap + (size_t)(c*16+lx)*1024 + k0s + quad*8, &smem[(BUF) + c*512]); \
        gload_lds16(Bp + (size_t)(c*16+lx)*1024 + k0s + quad*8, &smem[(BUF) + 4096 + c*512]); } }
#define GQ_COMP(BUF) { \
    f16x8 af[4], bf[4]; \
    for (int mt=0;mt<4;mt++) af[mt] = *(const f16x8*)&smem[(BUF) + (wm*4+mt)*512 + quad*128 + lx*8]; \
    for (int nt=0;nt<4;nt++) bf[nt] = *(const f16x8*)&smem[(BUF) + 4096 + (wn*4+nt)*512 + quad*128 + lx*8]; \
    for (int mt=0;mt<4;mt++) \
        for (int nt=0;nt<4;nt++) \
            acc[mt][nt] = MFMA16(af[mt], bf[nt], acc[mt][nt]); }

    GQ_STAGE(0, 0);
    __syncthreads();
    #pragma unroll 1
    for (int it=0; it<32; it+=2){
        if (it+1 < 32) GQ_STAGE(8192, it+1);
        GQ_COMP(0);
        __syncthreads();
        if (it+2 < 32) GQ_STAGE(0, it+2);
        GQ_COMP(8192);
        __syncthreads();
    }
    // epilogue: C-tile -> LDS -> dense f16x8 stores
    f16* Ct = smem;
    const bool isV = (n0 >= 2048);
    if (!isV){
        #pragma unroll
        for (int mt=0;mt<4;mt++){
            #pragma unroll
            for (int nt=0;nt<4;nt++){
                int n_loc = wn*64 + nt*16 + lx;
                float bv = bias[n0 + n_loc];
                #pragma unroll
                for (int r=0;r<4;r++){
                    int m_loc = wm*64 + mt*16 + quad*4 + r;
                    Ct[m_loc*CT_STRIDE + n_loc] = (f16)(acc[mt][nt][r] + bv);
                }
            }
        }
    } else {
        // transposed staging: Ct_t[n][m], r-quad contiguous -> f16x4 writes
        #pragma unroll
        for (int mt=0;mt<4;mt++){
            #pragma unroll
            for (int nt=0;nt<4;nt++){
                int n_loc = wn*64 + nt*16 + lx;
                float bv = bias[n0 + n_loc];
                int m_base = wm*64 + mt*16 + quad*4;
                f16x4 t4;
                #pragma unroll
                for (int r=0;r<4;r++) t4[r] = (f16)(acc[mt][nt][r] + bv);
                *(f16x4*)&Ct[n_loc*CTV_STRIDE + m_base] = t4;
            }
        }
    }
    __syncthreads();
    const int bb = m0 >> 10;
    if (!isV){
        for (int it=0; it<8; it++){
            int row = it*32 + wave*8 + (lane>>3);
            int ch  = lane & 7;
            int m_loc = row >> 1, half = row & 1;
            f16x8 v = *(const f16x8*)&Ct[m_loc*CT_STRIDE + half*64 + ch*8];
            int n = n0 + half*64;
            int which = n >> 10, cc = n & 1023, h = cc >> 6;
            int t = (m0 + m_loc) & 1023;
            f16* dst = (which==0) ? Qh : Kh;
            *(f16x8*)(dst + ((size_t)(bb*16+h)*1024 + t)*64 + ch*8) = v;
        }
    } else {
        for (int it=0; it<8; it++){
            int drow = it*16 + wave*4 + (lane>>4);
            int ch   = lane & 15;
            f16x8 v = *(const f16x8*)&Ct[drow*CTV_STRIDE + ch*8];
            int cc = (n0 + drow) & 1023;
            int h = cc >> 6, d = cc & 63;
            int t = (m0 + ch*8) & 1023;
            *(f16x8*)(Vt + ((size_t)(bb*16+h)*64 + d)*1024 + t) = v;
        }
    }
}

// ---------------------------------------------------------------------------
// GEMM proj: 128x64x32, global_load_lds staging + XCD swizzle; block 512 =
// finish_refr.
// ---------------------------------------------------------------------------
__global__ __launch_bounds__(256) void gemm_proj_k(
    const f16* __restrict__ A, const f16* __restrict__ Bt,
    const float* __restrict__ bias, float* __restrict__ out,
    const float* __restrict__ racc)
{
    if (blockIdx.x == 512){
        float* oref = out + (size_t)B_*T_*C_;
        #pragma unroll
        for (int j=0;j<16;j++){
            int idx = j*256 + threadIdx.x;
            oref[idx] = racc[idx] * (1.0f/(H_*T_));
        }
        return;
    }
    __shared__ __align__(16) f16 smem[12288];  // buf0 0..6143, buf1 6144..12287
    const int tid = threadIdx.x;
    const int lane = tid & 63, wave = tid >> 6;
    const int lx = lane & 15, quad = lane >> 4;
    const int wm = wave & 1, wn = wave >> 1;
    const int lin = blockIdx.x;                      // 0..511
    const int nb  = (lin & 7)*64 + (lin >> 3);       // bijective XCD chunking
    const int m0 = (nb >> 4)*128, n0 = (nb & 15)*64;
    const f16* Ap = A  + (size_t)m0*1024;
    const f16* Bp = Bt + (size_t)n0*1024;
    f32x4 acc[4][2];
    #pragma unroll
    for (int i=0;i<4;i++){
        #pragma unroll
        for (int j=0;j<2;j++){ acc[i][j][0]=0.f;acc[i][j][1]=0.f;acc[i][j][2]=0.f;acc[i][j][3]=0.f; }
    }
#define GP_STAGE(BUF, KT) { \
    const int k0s = (KT)*32; \
    for (int i=0;i<2;i++){ int c=i*4+wave; \
        gload_lds16(Ap + (size_t)(c*16+lx)*1024 + k0s + quad*8, &smem[(BUF) + c*512]); } \
    gload_lds16(Bp + (size_t)(wave*16+lx)*1024 + k0s + quad*8, &smem[(BUF) + 4096 + wave*512]); }
#define GP_COMP(BUF) { \
    f16x8 af[4], bf[2]; \
    for (int mt=0;mt<4;mt++) af[mt] = *(const f16x8*)&smem[(BUF) + (wm*4+mt)*512 + quad*128 + lx*8]; \
    for (int nt=0;nt<2;nt++) bf[nt] = *(const f16x8*)&smem[(BUF) + 4096 + (wn*2+nt)*512 + quad*128 + lx*8]; \
    for (int mt=0;mt<4;mt++) \
        for (int nt=0;nt<2;nt++) \
            acc[mt][nt] = MFMA16(af[mt], bf[nt], acc[mt][nt]); }

    GP_STAGE(0, 0);
    __syncthreads();
    #pragma unroll 1
    for (int it=0; it<32; it+=2){
        if (it+1 < 32) GP_STAGE(6144, it+1);
        GP_COMP(0);
        __syncthreads();
        if (it+2 < 32) GP_STAGE(0, it+2);
        GP_COMP(6144);
        __syncthreads();
    }
    #pragma unroll
    for (int mt=0;mt<4;mt++){
        #pragma unroll
        for (int nt=0;nt<2;nt++){
            int n = n0 + wn*32 + nt*16 + lx;
            float bv = bias[n];
            #pragma unroll
            for (int r=0;r<4;r++){
                int m = m0 + wm*64 + mt*16 + quad*4 + r;
                out[(size_t)m*1024 + n] = acc[mt][nt][r] + bv;
            }
        }
    }
}

// ---------------------------------------------------------------------------
// attn_stats (R4 known-good): LDS-staged K dbuf, single compute sweep ->
// Pbuf + row sums; reread -> colp column sums.
// ---------------------------------------------------------------------------
__global__ __launch_bounds__(256) void attn_stats_k(
    const f16* __restrict__ Qh, const f16* __restrict__ Kh,
    float* __restrict__ rowl, float* __restrict__ colp,
    f16* __restrict__ Pbuf)
{
    __shared__ __align__(16) f16 Kl[8192];   // bufA 0..4095, bufB 4096..8191
    __shared__ __align__(16) f16 Pl[4][16*72];
    __shared__ float invl_sh[64];
    const int tid = threadIdx.x;
    const int lane = tid & 63, wave = tid >> 6;
    const int lx = lane & 15, quad = lane >> 4;
    const int g  = 15 - (blockIdx.x >> 6);
    const int bh = blockIdx.x & 63;
    const int qpos = wave*16 + quad*4;
    const size_t kbase = (size_t)bh*65536;
    const int S = (g+1)*64;
    f16* __restrict__ Pblk = Pbuf + (size_t)bh*PSTRIDE_BH + (size_t)4096*((g*(g+1))>>1);

    const size_t qoff = ((size_t)bh*1024 + g*64 + wave*16 + lx)*64;
    f16x8 aq0 = *(const f16x8*)(Qh + qoff + quad*8);
    f16x8 aq1 = *(const f16x8*)(Qh + qoff + 32 + quad*8);

#define KLOAD(dst, KT) { \
    for (int i=0;i<2;i++){ int u=i*4+wave, cc=u&3, kh=u>>2; \
        dst[i] = *(const f16x8*)(Kh + kbase + (size_t)((KT)*64 + cc*16+lx)*64 + kh*32 + quad*8); } }
#define KSTORE(src, BUF) { \
    for (int i=0;i<2;i++){ int u=i*4+wave, cc=u&3, kh=u>>2; \
        *(f16x8*)&Kl[(BUF) + cc*1024 + kh*512 + quad*128 + lx*8] = src[i]; } }
#define STATS1_TILE(KT, BUF) { \
    const bool diag = ((KT) == g); \
    for (int nt=0;nt<4;nt++){ \
        f32x4 sc = {0.f,0.f,0.f,0.f}; \
        f16x8 b0 = *(const f16x8*)&Kl[(BUF) + nt*1024 + quad*128 + lx*8]; \
        f16x8 b1 = *(const f16x8*)&Kl[(BUF) + nt*1024 + 512 + quad*128 + lx*8]; \
        sc = MFMA16(aq0, b0, sc); \
        sc = MFMA16(aq1, b1, sc); \
        for (int r=0;r<4;r++){ \
            float sv = sc[r]; \
            if (diag && (nt*16+lx) > (qpos + r)) sv = -1e4f; \
            float p = EXP2(sv*K2E); \
            ls[r] += p; \
            Pl[wave][(quad*4+r)*72 + nt*16 + lx] = (f16)p; \
        } } \
    for (int it2=0; it2<2; it2++){ \
        int qq = it2*8 + (lane>>3), chh = lane & 7; \
        f16x8 v = *(const f16x8*)&Pl[wave][qq*72 + chh*8]; \
        *(f16x8*)(Pblk + (size_t)(wave*16+qq)*S + (KT)*64 + chh*8) = v; } }

    f16x8 rkE[2], rkO[2];
    float ls[4] = {0.f,0.f,0.f,0.f};
    // ---- single compute sweep ----
    KLOAD(rkE, 0);
    KSTORE(rkE, 0);
    if (g >= 1) KLOAD(rkO, 1);
    __syncthreads();
    #pragma unroll 1
    for (int kt=0; kt<=g; kt+=2){
        if (kt+2 <= g) KLOAD(rkE, kt+2);
        if (kt+1 <= g) KSTORE(rkO, 4096);
        STATS1_TILE(kt, 0);
        __syncthreads();
        if (kt+1 <= g){
            if (kt+3 <= g) KLOAD(rkO, kt+3);
            if (kt+2 <= g) KSTORE(rkE, 0);
            STATS1_TILE(kt+1, 4096);
            __syncthreads();
        }
    }
    #pragma unroll
    for (int r=0;r<4;r++){
        float l = qsum_(ls[r]);
        if (lx == 0){
            rowl[(size_t)bh*1024 + g*64 + qpos + r] = l;
            invl_sh[qpos + r] = RCP(l);
        }
    }
    __syncthreads();   // invl_sh + Pblk global writes visible block-wide
    // ---- reread sweep: column sums of probs ----
    if (tid < (g+1)*16){
        const int k0 = tid*4;
        float a0=0.f, a1=0.f, a2=0.f, a3=0.f;
        const f16* pr = Pblk + k0;
        #pragma unroll 4
        for (int q=0;q<64;q++){
            f16x4 v = *(const f16x4*)(pr + (size_t)q*S);
            float w = invl_sh[q];
            a0 += (float)v[0]*w; a1 += (float)v[1]*w;
            a2 += (float)v[2]*w; a3 += (float)v[3]*w;
        }
        float* cp = colp + (size_t)bh*1024 + k0;
        atomicAdd(cp+0,a0); atomicAdd(cp+1,a1);
        atomicAdd(cp+2,a2); atomicAdd(cp+3,a3);
    }
}

// ---------------------------------------------------------------------------
// attn_apply (R8 best-known): LDS-staged V dbuf + in-register LIF in the
// MFMA A-fragment layout; Pl used only for the Yh epilogue. Reread
// recomputes LIF (f32) -> racc column sums.
// ---------------------------------------------------------------------------
__global__ __launch_bounds__(256) void attn_apply_k(
    const f16* __restrict__ Vt,
    const float* __restrict__ rowl,
    const float* __restrict__ colp, const float* __restrict__ refr,
    const float* __restrict__ threshold, const float* __restrict__ leak,
    const float* __restrict__ steepness, const float* __restrict__ ref_strength,
    const float* __restrict__ cross_w,
    f16* __restrict__ Yh, float* __restrict__ racc,
    f16* __restrict__ Pbuf)
{
    __shared__ __align__(16) f16 Vl[8192];
    __shared__ __align__(16) f16 Pl[4][16*72];   // epilogue staging only
    __shared__ float eb[1024];
    __shared__ float invl_sh[64];
    __shared__ float invD_sh[64];
    const int tid = threadIdx.x;
    const int lane = tid & 63, wave = tid >> 6;
    const int lx = lane & 15, quad = lane >> 4;
    const int g  = 15 - (blockIdx.x >> 6);
    const int bh = blockIdx.x & 63;
    const int b  = bh >> 4, h = bh & 15;
    const size_t kbase = (size_t)bh*65536;
    const int S = (g+1)*64;
    f16* __restrict__ Pblk = Pbuf + (size_t)bh*PSTRIDE_BH + (size_t)4096*((g*(g+1))>>1);

    const float thr = fabsf(threshold[h])*0.1f;
    const float lk  = sigmoidf_(leak[h]);
    const float st2 = softplusf_(steepness[h]) * LOG2E;
    const float sprT= softplusf_(ref_strength[h]) * (1.0f/T_);
    const float cw  = sigmoidf_(cross_w[h]);
    const float Alk = 1.f - lk;

    {
        float4 cp = *(const float4*)(colp + (size_t)bh*1024 + tid*4);
        float4 rf = *(const float4*)(refr + (size_t)b*1024 + tid*4);
        eb[tid*4+0] = st2*(thr + sprT*cp.x + cw*rf.x);
        eb[tid*4+1] = st2*(thr + sprT*cp.y + cw*rf.y);
        eb[tid*4+2] = st2*(thr + sprT*cp.z + cw*rf.z);
        eb[tid*4+3] = st2*(thr + sprT*cp.w + cw*rf.w);
    }
    if (tid < 64) invl_sh[tid] = RCP(rowl[(size_t)bh*1024 + g*64 + tid]);
    __syncthreads();   // eb + invl_sh visible

    const float wli = invl_sh[wave*16 + lx];   // this lane's row 1/l

    f32x4 y[4];
    #pragma unroll
    for (int i=0;i<4;i++){ y[i][0]=0.f;y[i][1]=0.f;y[i][2]=0.f;y[i][3]=0.f; }
    float Dp = 0.f;

#define VLOAD(dst, KT) { \
    for (int i=0;i<2;i++){ int u=i*4+wave, cc=u&3, kh=u>>2; \
        dst[i] = *(const f16x8*)(Vt + kbase + (size_t)(cc*16+lx)*1024 + (KT)*64 + kh*32 + quad*8); } }
#define VSTORE(src, BUF) { \
    for (int i=0;i<2;i++){ int u=i*4+wave, cc=u&3, kh=u>>2; \
        *(f16x8*)&Vl[(BUF) + cc*1024 + kh*512 + quad*128 + lx*8] = src[i]; } }
// p A-fragment loads: pv[kh][j] = p[q=wave*16+lx][k=KT*64+kh*32+quad*8+j]
#define PLOADX(dst, KT) { \
    const f16* pp = Pblk + (size_t)(wave*16 + lx)*S + (KT)*64 + quad*8; \
    dst[0] = *(const f16x8*)(pp); \
    dst[1] = *(const f16x8*)(pp + 32); }
#define APPLY_T(KT, BUF, pv) { \
    const float* ebp = &eb[(KT)*64 + quad*8]; \
    float4 eA0 = *(const float4*)(ebp); \
    float4 eA1 = *(const float4*)(ebp+4); \
    float4 eB0 = *(const float4*)(ebp+32); \
    float4 eB1 = *(const float4*)(ebp+36); \
    float ea[8] = {eA0.x,eA0.y,eA0.z,eA0.w,eA1.x,eA1.y,eA1.z,eA1.w}; \
    float ebb[8] = {eB0.x,eB0.y,eB0.z,eB0.w,eB1.x,eB1.y,eB1.z,eB1.w}; \
    f16x8 af0, af1; \
    for (int jj=0;jj<8;jj++){ \
        float p = (float)pv[0][jj] * wli; \
        float fire = RCP(1.f + EXP2(ea[jj] - st2*p)); \
        float pw = p*(lk + Alk*fire); \
        Dp += pw; af0[jj] = (f16)pw; } \
    for (int jj=0;jj<8;jj++){ \
        float p = (float)pv[1][jj] * wli; \
        float fire = RCP(1.f + EXP2(ebb[jj] - st2*p)); \
        float pw = p*(lk + Alk*fire); \
        Dp += pw; af1[jj] = (f16)pw; } \
    for (int dt=0;dt<4;dt++){ \
        f16x8 bv0 = *(const f16x8*)&Vl[(BUF) + dt*1024 + quad*128 + lx*8]; \
        f16x8 bv1 = *(const f16x8*)&Vl[(BUF) + dt*1024 + 512 + quad*128 + lx*8]; \
        y[dt] = MFMA16(af0, bv0, y[dt]); \
        y[dt] = MFMA16(af1, bv1, y[dt]); } }

    f16x8 rvE[2], rvO[2], pvE[2], pvO[2];
    VLOAD(rvE, 0); PLOADX(pvE, 0);
    VSTORE(rvE, 0);
    if (g >= 1){ VLOAD(rvO, 1); PLOADX(pvO, 1); }
    __syncthreads();
    #pragma unroll 1
    for (int kt=0; kt<=g; kt+=2){
        if (kt+2 <= g) VLOAD(rvE, kt+2);
        if (kt+1 <= g) VSTORE(rvO, 4096);
        APPLY_T(kt, 0, pvE);
        if (kt+2 <= g) PLOADX(pvE, kt+2);
        __syncthreads();
        if (kt+1 <= g){
            if (kt+3 <= g) VLOAD(rvO, kt+3);
            if (kt+2 <= g) VSTORE(rvE, 0);
            APPLY_T(kt+1, 4096, pvO);
            if (kt+3 <= g) PLOADX(pvO, kt+3);
            __syncthreads();
        }
    }
    // row-sum D reduce across the 4 quad lanes of each row (q = wave*16+lx)
    Dp += __shfl_xor(Dp,16,64); Dp += __shfl_xor(Dp,32,64);
    if (quad == 0) invD_sh[wave*16 + lx] = RCP(Dp + 1e-8f);

    // y normalize -> Yh (via Pl staging; same-wave LDS ordering only)
    float invD[4];
    #pragma unroll
    for (int r=0;r<4;r++) invD[r] = invD_sh[wave*16 + quad*4 + r];
    #pragma unroll
    for (int dt=0;dt<4;dt++){
        #pragma unroll
        for (int r=0;r<4;r++)
            Pl[wave][(quad*4+r)*72 + dt*16 + lx] = (f16)(y[dt][r]*invD[r]);
    }
    #pragma unroll
    for (int it=0; it<2; it++){
        int q = it*8 + (lane>>3), ch = lane & 7;
        f16x8 v = *(const f16x8*)&Pl[wave][q*72 + ch*8];
        *(f16x8*)(Yh + (size_t)(b*1024 + g*64 + wave*16 + q)*1024 + h*64 + ch*8) = v;
    }

    __syncthreads();   // all waves' invD_sh visible

    // ---- reread sweep: recompute pw from p (f32), column sums * invD ----
    if (tid < (g+1)*16){
        const int k0 = tid*4;
        float4 ebv = *(const float4*)&eb[k0];
        float a0=0.f, a1=0.f, a2=0.f, a3=0.f;
        const f16* pr = Pblk + k0;
        #pragma unroll 4
        for (int q=0;q<64;q++){
            f16x4 v = *(const f16x4*)(pr + (size_t)q*S);
            float wl = invl_sh[q], wd = invD_sh[q];
            float p0 = (float)v[0]*wl, p1 = (float)v[1]*wl;
            float p2 = (float)v[2]*wl, p3 = (float)v[3]*wl;
            float f0 = RCP(1.f + EXP2(ebv.x - st2*p0));
            float f1 = RCP(1.f + EXP2(ebv.y - st2*p1));
            float f2 = RCP(1.f + EXP2(ebv.z - st2*p2));
            float f3 = RCP(1.f + EXP2(ebv.w - st2*p3));
            a0 += p0*(lk + Alk*f0)*wd; a1 += p1*(lk + Alk*f1)*wd;
            a2 += p2*(lk + Alk*f2)*wd; a3 += p3*(lk + Alk*f3)*wd;
        }
        float* rp = racc + (size_t)b*1024 + k0;
        atomicAdd(rp+0,a0); atomicAdd(rp+1,a1);
        atomicAdd(rp+2,a2); atomicAdd(rp+3,a3);
    }
}

// ---------------------------------------------------------------------------
extern "C" void kernel_launch(void* const* d_in, const int* in_sizes, int n_in,
                              void* d_out, int out_size, void* d_ws, size_t ws_size,
                              hipStream_t stream) {
    (void)in_sizes; (void)n_in; (void)out_size; (void)ws_size;
    const float* x           = (const float*)d_in[0];
    const float* refr        = (const float*)d_in[1];
    const float* W_attn      = (const float*)d_in[2];
    const float* b_attn      = (const float*)d_in[3];
    const float* W_proj      = (const float*)d_in[4];
    const float* b_proj      = (const float*)d_in[5];
    const float* threshold   = (const float*)d_in[6];
    const float* leak        = (const float*)d_in[7];
    const float* steepness   = (const float*)d_in[8];
    const float* ref_strength= (const float*)d_in[9];
    const float* cross_w     = (const float*)d_in[10];
    float* out = (float*)d_out;

    char* ws = (char*)d_ws;
    f16* x_h = (f16*)ws;                       ws += (size_t)4096*1024*2;
    f16* WaT = (f16*)ws;                       ws += (size_t)3072*1024*2;
    f16* WpT = (f16*)ws;                       ws += (size_t)1024*1024*2;
    f16* Qh  = (f16*)ws;                       ws += (size_t)64*1024*64*2;
    f16* Kh  = (f16*)ws;                       ws += (size_t)64*1024*64*2;
    f16* Vt  = (f16*)ws;                       ws += (size_t)64*64*1024*2;
    f16* Yh  = (f16*)ws;                       ws += (size_t)4096*1024*2;
    float* rowl = (float*)ws;                  ws += (size_t)65536*4;
    float* colp = (float*)ws;                  ws += (size_t)65536*4;
    float* racc = (float*)ws;                  ws += (size_t)4096*4;   // adjacent to colp!
    f16* Pbuf = (f16*)ws;                      ws += (size_t)64*PSTRIDE_BH*2;

    prep_k<<<dim3(6212), dim3(256), 0, stream>>>(x, W_attn, W_proj, x_h, WaT, WpT, colp);
    gemm_qkv_k<<<dim3(24,32), dim3(256), 0, stream>>>(x_h, WaT, b_attn, Qh, Kh, Vt);
    attn_stats_k<<<dim3(1024), dim3(256), 0, stream>>>(Qh, Kh, rowl, colp, Pbuf);
    attn_apply_k<<<dim3(1024), dim3(256), 0, stream>>>(
        Vt, rowl, colp, refr,
        threshold, leak, steepness, ref_strength, cross_w, Yh, racc, Pbuf);
    gemm_proj_k<<<dim3(513), dim3(256), 0, stream>>>(Yh, WpT, b_proj, out, racc);
}